// Round 3
// baseline (4649.412 us; speedup 1.0000x reference)
//
#include <hip/hip_runtime.h>

// ---------------- problem constants ----------------
#define NLAT 1228760
#define RATE_OFF 5529600      // 2*3*921600
#define BPD_OFF 6758360
#define NB_ARM 4800           // ceil(NLAT/256)
#define LSC 13.8155f

// grid sizes: (720,1280)(360,640)(180,320)(90,160)(45,80)(23,40)(12,20)
static __device__ const int d_GOFF[8] = {0,921600,1152000,1209600,1224000,1227600,1228520,1228760};
static __device__ const int d_GW[7]   = {1280,640,320,160,80,40,20};
static __device__ const int d_XOFF[7] = {0,6451200,7833600,8121600,8179200,8190000,8191840};

#define XP_OFF   8192080   // staging for depthwise pre-conv output (max 6*230400 = 1382400)
#define S1_OFF   9574480   // 6*921600
#define BSUM_OFF 15104080  // NB_ARM partial sums
#define CNT_OFF  15108992  // barrier counter (unsigned), zeroed by k_quant

#define NB_MEGA 1024
#define GSTRIDE (NB_MEGA*256)

// 24 causal context offsets
static __device__ const int d_DR[24] = {-4,-3,-3,-3,-3,-3,-2,-2,-2,-2,-2,-2,-2,-1,-1,-1,-1,-1,-1,-1, 0, 0, 0, 0};
static __device__ const int d_DC[24] = { 0,-2,-1, 0, 1, 2,-3,-2,-1, 0, 1, 2, 3,-3,-2,-1, 0, 1, 2, 3,-4,-3,-2,-1};

__device__ __forceinline__ float softround_f(float x) {
    float fl = floorf(x);
    float d = x - fl - 0.5f;
    // tanh(d/0.3) = (e^{2d/0.3}-1)/(e^{2d/0.3}+1), arg in [-1.67,1.67]
    float t = __expf(d * 6.6666667f);
    float th = __fdividef(t - 1.0f, t + 1.0f);
    return fl + 0.5f + 0.53699369f * th;
}

// ---------------- grid barrier (all NB_MEGA blocks co-resident) ----------------
__device__ __forceinline__ void gbar(unsigned* cnt, unsigned target) {
    __threadfence();                       // release my writes (drains to L2, device scope)
    __syncthreads();
    if (threadIdx.x == 0) {
        __hip_atomic_fetch_add(cnt, 1u, __ATOMIC_ACQ_REL, __HIP_MEMORY_SCOPE_AGENT);
        while (__hip_atomic_load(cnt, __ATOMIC_ACQUIRE, __HIP_MEMORY_SCOPE_AGENT) < target)
            __builtin_amdgcn_s_sleep(1);
    }
    __syncthreads();
    __threadfence();                       // acquire: invalidate L1 so fresh data is seen
}

// ---------------- 1. quantize (also zeros the barrier counter) ----------------
__global__ __launch_bounds__(256) void k_quant(
    const float* __restrict__ l0, const float* __restrict__ l1,
    const float* __restrict__ l2, const float* __restrict__ l3,
    const float* __restrict__ l4, const float* __restrict__ l5,
    const float* __restrict__ l6, float* __restrict__ ws)
{
    int t = blockIdx.x*256 + threadIdx.x;
    if (t == 0) {
        unsigned* cnt = (unsigned*)(ws + CNT_OFF);
        __hip_atomic_store(cnt, 0u, __ATOMIC_RELAXED, __HIP_MEMORY_SCOPE_AGENT);
    }
    if (t >= NLAT) return;
    int g = 0;
    #pragma unroll
    for (int i = 1; i < 7; ++i) if (t >= d_GOFF[i]) g = i;
    int local = t - d_GOFF[g];
    const float* lp = l0;
    if      (g==1) lp=l1; else if (g==2) lp=l2; else if (g==3) lp=l3;
    else if (g==4) lp=l4; else if (g==5) lp=l5; else if (g==6) lp=l6;
    ws[d_XOFF[g] + local] = softround_f(lp[local] * 16.0f);
}

// ---------------- 2. ARM ----------------
__global__ __launch_bounds__(256) void k_arm(
    const float* __restrict__ ws,
    const float* __restrict__ w0, const float* __restrict__ b0,
    const float* __restrict__ w1, const float* __restrict__ b1,
    const float* __restrict__ wo, const float* __restrict__ bo,
    float* __restrict__ out_rate, float* __restrict__ bsum)
{
    int t = blockIdx.x*256 + threadIdx.x;
    float rate = 0.0f;
    if (t < NLAT) {
        int g = 0;
        #pragma unroll
        for (int i = 1; i < 7; ++i) if (t >= d_GOFF[i]) g = i;
        int local = t - d_GOFF[g];
        int w = d_GW[g];
        int y = (int)((unsigned)local / (unsigned)w);
        int x = local - y*w;
        const float* __restrict__ q = ws + d_XOFF[g];

        float ctx[24];
        if (y >= 4 && x >= 4 && x < w-4) {
            const float* base = q + y*w + x;
            #pragma unroll
            for (int k = 0; k < 24; ++k)
                ctx[k] = base[d_DR[k]*w + d_DC[k]];
        } else {
            #pragma unroll
            for (int k = 0; k < 24; ++k) {
                int yy = y + d_DR[k];
                int xx = x + d_DC[k];
                float v = 0.0f;
                if (yy >= 0 && (unsigned)xx < (unsigned)w) v = q[yy*w + xx];
                ctx[k] = v;
            }
        }

        float h0[24];
        #pragma unroll
        for (int j = 0; j < 24; ++j) h0[j] = b0[j];
        #pragma unroll
        for (int k = 0; k < 24; ++k) {
            float c = ctx[k];
            #pragma unroll
            for (int j = 0; j < 24; ++j) h0[j] = fmaf(c, w0[k*24+j], h0[j]);
        }
        #pragma unroll
        for (int j = 0; j < 24; ++j) h0[j] = fmaxf(h0[j], 0.0f);

        float h1[24];
        #pragma unroll
        for (int j = 0; j < 24; ++j) h1[j] = b1[j];
        #pragma unroll
        for (int k = 0; k < 24; ++k) {
            float c = h0[k];
            #pragma unroll
            for (int j = 0; j < 24; ++j) h1[j] = fmaf(c, w1[k*24+j], h1[j]);
        }
        #pragma unroll
        for (int j = 0; j < 24; ++j) h1[j] = fmaxf(h1[j], 0.0f);

        float o0 = bo[0], o1 = bo[1];
        #pragma unroll
        for (int j = 0; j < 24; ++j) {
            o0 = fmaf(h1[j], wo[2*j+0], o0);
            o1 = fmaf(h1[j], wo[2*j+1], o1);
        }

        float mu = o0;
        float ls = fminf(fmaxf(o1, -LSC), LSC);
        float inv_s = __expf(0.5f * ls);

        float xv = q[y*w + x];
        float a = xv + 0.5f - mu;
        float b = xv - 0.5f - mu;
        // CDF(d) = 0.5 - 0.5*sign(d)*(exp(-|d|/s)-1); proba = CDF(a)-CDF(b), branch-free:
        float ka = __expf(-fabsf(a) * inv_s);
        float kb = __expf(-fabsf(b) * inv_s);
        float sa = copysignf(1.0f, a);
        float sb = copysignf(1.0f, b);
        float proba = 0.5f * (sb*(kb - 1.0f) - sa*(ka - 1.0f));
        proba = fmaxf(proba, 1.52587890625e-05f);
        rate = -__log2f(proba);
        out_rate[t] = rate;
    }

    __shared__ float sm[256];
    sm[threadIdx.x] = rate;
    __syncthreads();
    #pragma unroll
    for (int st = 128; st > 0; st >>= 1) {
        if (threadIdx.x < st) sm[threadIdx.x] += sm[threadIdx.x + st];
        __syncthreads();
    }
    if (threadIdx.x == 0) bsum[blockIdx.x] = sm[0];
}

// ---------------- mega-kernel sections ----------------
template<int CH,int H,int W>
__device__ __forceinline__ void sec_pre(const float* __restrict__ xin, float* __restrict__ xp,
                                        const float* __restrict__ k7, int gtid)
{
    for (int idx = gtid; idx < CH*H*W; idx += GSTRIDE) {
        int c = idx / (H*W);
        int rem = idx - c*(H*W);
        int y = rem / W;
        int x = rem - y*W;
        const float* p = xin + c*H*W;
        float acc = 0.0f;
        if (x >= 3 && x < W-3 && y >= 3 && y < H-3) {
            const float* q = p + (y-3)*W + (x-3);
            #pragma unroll
            for (int a = 0; a < 7; ++a)
                #pragma unroll
                for (int b = 0; b < 7; ++b)
                    acc = fmaf(q[a*W + b], k7[a*7 + b], acc);
        } else {
            #pragma unroll
            for (int a = 0; a < 7; ++a) {
                int yy = y + a - 3;
                if (yy < 0 || yy >= H) continue;
                #pragma unroll
                for (int b = 0; b < 7; ++b) {
                    int xx = x + b - 3;
                    if (xx < 0 || xx >= W) continue;
                    acc = fmaf(p[yy*W + xx], k7[a*7 + b], acc);
                }
            }
        }
        xp[idx] = acc;
    }
}

// convT 8x8 stride2 + crop 3: y[p,q] = sum_{a,b parity-matched} x[(p+a-4)/2][(q+b-4)/2]*k[a,b]
template<int CH,int H,int W,int HT,int WT>
__device__ __forceinline__ void sec_ups(const float* __restrict__ xp, float* __restrict__ xout,
                                        const float* __restrict__ k8, int gtid)
{
    constexpr int HB = (HT+1)/2, WB = (WT+1)/2;
    for (int idx = gtid; idx < CH*HB*WB; idx += GSTRIDE) {
        int c = idx / (HB*WB);
        int rem = idx - c*(HB*WB);
        int pb = rem / WB;
        int qb = rem - pb*WB;
        const float* __restrict__ src = xp + c*H*W;

        float in[5][5];
        #pragma unroll
        for (int r = 0; r < 5; ++r) {
            int i = pb - 2 + r;
            bool rv = (i >= 0) && (i < H);
            #pragma unroll
            for (int s = 0; s < 5; ++s) {
                int j = qb - 2 + s;
                in[r][s] = (rv && j >= 0 && j < W) ? src[i*W + j] : 0.0f;
            }
        }

        float* __restrict__ dst = xout + (c+1)*HT*WT;
        #pragma unroll
        for (int pp = 0; pp < 2; ++pp) {
            int p = 2*pb + pp;
            if (p >= HT) break;
            #pragma unroll
            for (int qq = 0; qq < 2; ++qq) {
                int q = 2*qb + qq;
                if (q >= WT) continue;
                float acc = 0.0f;
                #pragma unroll
                for (int t = 0; t < 4; ++t)
                    #pragma unroll
                    for (int u = 0; u < 4; ++u)
                        acc = fmaf(in[pp+t][qq+u], k8[(pp+2*t)*8 + (qq+2*u)], acc);
                dst[p*WT + q] = acc;
            }
        }
    }
}

__device__ __forceinline__ void sec_syn01(const float* __restrict__ x0,
    const float* __restrict__ w0, const float* __restrict__ b0,
    const float* __restrict__ w1, const float* __restrict__ b1,
    float* __restrict__ s1, int gtid)
{
    for (int pix = gtid; pix < 921600; pix += GSTRIDE) {
        float in[7];
        #pragma unroll
        for (int c = 0; c < 7; ++c) in[c] = x0[c*921600 + pix];
        float h[48];
        #pragma unroll
        for (int o = 0; o < 48; ++o) {
            float a = b0[o];
            #pragma unroll
            for (int c = 0; c < 7; ++c) a = fmaf(in[c], w0[o*7 + c], a);
            h[o] = fmaxf(a, 0.0f);
        }
        #pragma unroll
        for (int o = 0; o < 6; ++o) {
            float a = b1[o];
            #pragma unroll
            for (int c = 0; c < 48; ++c) a = fmaf(h[c], w1[o*48 + c], a);
            s1[o*921600 + pix] = a;
        }
    }
}

template<bool RELU_RES>
__device__ __forceinline__ void sec_conv3(const float* __restrict__ sin,
    const float* __restrict__ wc, const float* __restrict__ bc,
    float* __restrict__ sout, int gtid)
{
    for (int pix = gtid; pix < 921600; pix += GSTRIDE) {
        int y = pix / 1280;
        int x = pix - y*1280;
        float acc[6];
        #pragma unroll
        for (int o = 0; o < 6; ++o) acc[o] = bc[o];
        if (x >= 1 && x < 1279 && y >= 1 && y < 719) {
            #pragma unroll
            for (int ci = 0; ci < 6; ++ci) {
                const float* p = sin + ci*921600 + pix;
                #pragma unroll
                for (int dy = 0; dy < 3; ++dy)
                    #pragma unroll
                    for (int dx = 0; dx < 3; ++dx) {
                        float v = p[(dy-1)*1280 + dx - 1];
                        #pragma unroll
                        for (int o = 0; o < 6; ++o)
                            acc[o] = fmaf(v, wc[(o*6 + ci)*9 + dy*3 + dx], acc[o]);
                    }
            }
        } else {
            #pragma unroll
            for (int ci = 0; ci < 6; ++ci) {
                const float* p = sin + ci*921600;
                #pragma unroll
                for (int dy = 0; dy < 3; ++dy) {
                    int yy = y + dy - 1;
                    if (yy < 0 || yy >= 720) continue;
                    #pragma unroll
                    for (int dx = 0; dx < 3; ++dx) {
                        int xx = x + dx - 1;
                        if (xx < 0 || xx >= 1280) continue;
                        float v = p[yy*1280 + xx];
                        #pragma unroll
                        for (int o = 0; o < 6; ++o)
                            acc[o] = fmaf(v, wc[(o*6 + ci)*9 + dy*3 + dx], acc[o]);
                    }
                }
            }
        }
        if (RELU_RES) {
            #pragma unroll
            for (int o = 0; o < 6; ++o)
                sout[o*921600 + pix] = fmaxf(acc[o] + sin[o*921600 + pix], 0.0f);
        } else {
            // final layer: emit mu / scale directly
            #pragma unroll
            for (int o = 0; o < 6; ++o) {
                float v = acc[o] + sin[o*921600 + pix];
                if (o < 3) {
                    sout[o*921600 + pix] = v;
                } else {
                    float ls = fminf(fmaxf(v, -LSC), LSC);
                    sout[2764800 + (o-3)*921600 + pix] = __expf(-0.5f * ls);
                }
            }
        }
    }
}

__device__ __forceinline__ void do_bpd_reduce(const float* __restrict__ bsum, float* __restrict__ out_bpd)
{
    __shared__ float sm[256];
    float s = 0.0f;
    for (int i = threadIdx.x; i < NB_ARM; i += 256) s += bsum[i];
    sm[threadIdx.x] = s;
    __syncthreads();
    #pragma unroll
    for (int st = 128; st > 0; st >>= 1) {
        if (threadIdx.x < st) sm[threadIdx.x] += sm[threadIdx.x + st];
        __syncthreads();
    }
    if (threadIdx.x == 0) out_bpd[0] = sm[0] * (1.0f/2764800.0f);
}

// ---------------- 3. mega: ups chain + synthesis + bpd, one launch ----------------
__global__ __launch_bounds__(256, 4) void k_mega(
    float* __restrict__ ws,
    const float* __restrict__ pre_k, const float* __restrict__ ups_k,
    const float* __restrict__ syn_w0, const float* __restrict__ syn_b0,
    const float* __restrict__ syn_w1, const float* __restrict__ syn_b1,
    const float* __restrict__ syn_w2, const float* __restrict__ syn_b2,
    const float* __restrict__ syn_w3, const float* __restrict__ syn_b3,
    float* __restrict__ out)
{
    unsigned* cnt = (unsigned*)(ws + CNT_OFF);
    int gtid = blockIdx.x*256 + threadIdx.x;
    float* xp = ws + XP_OFF;

    // S0: bpd reduce on last block; pre step0 on the rest (240 elems)
    if (blockIdx.x == NB_MEGA-1) do_bpd_reduce(ws + BSUM_OFF, out + BPD_OFF);
    sec_pre<1,12,20>(ws + 8191840, xp, pre_k + 0*49, gtid);
    gbar(cnt, NB_MEGA*1);
    sec_ups<1,12,20,23,40>(xp, ws + 8190000, ups_k + 0*64, gtid);
    gbar(cnt, NB_MEGA*2);

    sec_pre<2,23,40>(ws + 8190000, xp, pre_k + 1*49, gtid);
    gbar(cnt, NB_MEGA*3);
    sec_ups<2,23,40,45,80>(xp, ws + 8179200, ups_k + 1*64, gtid);
    gbar(cnt, NB_MEGA*4);

    sec_pre<3,45,80>(ws + 8179200, xp, pre_k + 2*49, gtid);
    gbar(cnt, NB_MEGA*5);
    sec_ups<3,45,80,90,160>(xp, ws + 8121600, ups_k + 2*64, gtid);
    gbar(cnt, NB_MEGA*6);

    sec_pre<4,90,160>(ws + 8121600, xp, pre_k + 3*49, gtid);
    gbar(cnt, NB_MEGA*7);
    sec_ups<4,90,160,180,320>(xp, ws + 7833600, ups_k + 3*64, gtid);
    gbar(cnt, NB_MEGA*8);

    sec_pre<5,180,320>(ws + 7833600, xp, pre_k + 4*49, gtid);
    gbar(cnt, NB_MEGA*9);
    sec_ups<5,180,320,360,640>(xp, ws + 6451200, ups_k + 4*64, gtid);
    gbar(cnt, NB_MEGA*10);

    sec_pre<6,360,640>(ws + 6451200, xp, pre_k + 5*49, gtid);
    gbar(cnt, NB_MEGA*11);
    sec_ups<6,360,640,720,1280>(xp, ws + 0, ups_k + 5*64, gtid);
    gbar(cnt, NB_MEGA*12);

    sec_syn01(ws + 0, syn_w0, syn_b0, syn_w1, syn_b1, ws + S1_OFF, gtid);
    gbar(cnt, NB_MEGA*13);
    sec_conv3<true >(ws + S1_OFF, syn_w2, syn_b2, ws + 0, gtid);   // s2 reuses x0 buffer
    gbar(cnt, NB_MEGA*14);
    sec_conv3<false>(ws + 0, syn_w3, syn_b3, out, gtid);
}

// ---------------- host ----------------
extern "C" void kernel_launch(void* const* d_in, const int* in_sizes, int n_in,
                              void* d_out, int out_size, void* d_ws, size_t ws_size,
                              hipStream_t stream)
{
    const float* lat[7];
    for (int i = 0; i < 7; ++i) lat[i] = (const float*)d_in[i];
    const float* arm_w0  = (const float*)d_in[7];
    const float* arm_b0  = (const float*)d_in[8];
    const float* arm_w1  = (const float*)d_in[9];
    const float* arm_b1  = (const float*)d_in[10];
    const float* arm_wo  = (const float*)d_in[11];
    const float* arm_bo  = (const float*)d_in[12];
    const float* pre_k   = (const float*)d_in[13];
    const float* ups_k   = (const float*)d_in[14];
    const float* syn_w0  = (const float*)d_in[15];
    const float* syn_b0  = (const float*)d_in[16];
    const float* syn_w1  = (const float*)d_in[17];
    const float* syn_b1  = (const float*)d_in[18];
    const float* syn_w2  = (const float*)d_in[19];
    const float* syn_b2  = (const float*)d_in[20];
    const float* syn_w3  = (const float*)d_in[21];
    const float* syn_b3  = (const float*)d_in[22];

    float* out = (float*)d_out;
    float* ws  = (float*)d_ws;

    k_quant<<<dim3(NB_ARM), dim3(256), 0, stream>>>(
        lat[0],lat[1],lat[2],lat[3],lat[4],lat[5],lat[6], ws);

    k_arm<<<dim3(NB_ARM), dim3(256), 0, stream>>>(
        ws, arm_w0, arm_b0, arm_w1, arm_b1, arm_wo, arm_bo,
        out + RATE_OFF, ws + BSUM_OFF);

    k_mega<<<dim3(NB_MEGA), dim3(256), 0, stream>>>(
        ws, pre_k, ups_k,
        syn_w0, syn_b0, syn_w1, syn_b1, syn_w2, syn_b2, syn_w3, syn_b3,
        out);
}

// Round 4
// 311.028 us; speedup vs baseline: 14.9486x; 14.9486x over previous
//
#include <hip/hip_runtime.h>

// ---------------- problem constants ----------------
#define NLAT 1228760
#define RATE_OFF 5529600      // 2*3*921600
#define BPD_OFF 6758360
#define NB_ARM 4800           // ceil(NLAT/256)
#define LSC 13.8155f

// grid sizes: (720,1280)(360,640)(180,320)(90,160)(45,80)(23,40)(12,20)
static __device__ const int d_GOFF[8] = {0,921600,1152000,1209600,1224000,1227600,1228520,1228760};
static __device__ const int d_GW[7]   = {1280,640,320,160,80,40,20};
static __device__ const int d_XOFF[7] = {0,6451200,7833600,8121600,8179200,8190000,8191840};

#define S1_OFF   9574480   // 6*921600
#define BSUM_OFF 15104080  // NB_ARM partial sums
// s2 reuses x0 buffer (offset 0, 6451200 >= 5529600)

// 24 causal context offsets
static __device__ const int d_DR[24] = {-4,-3,-3,-3,-3,-3,-2,-2,-2,-2,-2,-2,-2,-1,-1,-1,-1,-1,-1,-1, 0, 0, 0, 0};
static __device__ const int d_DC[24] = { 0,-2,-1, 0, 1, 2,-3,-2,-1, 0, 1, 2, 3,-3,-2,-1, 0, 1, 2, 3,-4,-3,-2,-1};

__device__ __forceinline__ float softround_f(float x) {
    float fl = floorf(x);
    float d = x - fl - 0.5f;
    float t = __expf(d * 6.6666667f);
    float th = __fdividef(t - 1.0f, t + 1.0f);
    return fl + 0.5f + 0.53699369f * th;
}

// ---------------- 1. quantize ----------------
__global__ __launch_bounds__(256) void k_quant(
    const float* __restrict__ l0, const float* __restrict__ l1,
    const float* __restrict__ l2, const float* __restrict__ l3,
    const float* __restrict__ l4, const float* __restrict__ l5,
    const float* __restrict__ l6, float* __restrict__ ws)
{
    int t = blockIdx.x*256 + threadIdx.x;
    if (t >= NLAT) return;
    int g = 0;
    #pragma unroll
    for (int i = 1; i < 7; ++i) if (t >= d_GOFF[i]) g = i;
    int local = t - d_GOFF[g];
    const float* lp = l0;
    if      (g==1) lp=l1; else if (g==2) lp=l2; else if (g==3) lp=l3;
    else if (g==4) lp=l4; else if (g==5) lp=l5; else if (g==6) lp=l6;
    ws[d_XOFF[g] + local] = softround_f(lp[local] * 16.0f);
}

// ---------------- ARM body (validated R3 math) ----------------
__device__ __forceinline__ void arm_body(
    const float* __restrict__ ws,
    const float* __restrict__ w0, const float* __restrict__ b0,
    const float* __restrict__ w1, const float* __restrict__ b1,
    const float* __restrict__ wo, const float* __restrict__ bo,
    float* __restrict__ out_rate, float* __restrict__ bsum, int ablk)
{
    int t = ablk*256 + threadIdx.x;
    float rate = 0.0f;
    if (t < NLAT) {
        int g = 0;
        #pragma unroll
        for (int i = 1; i < 7; ++i) if (t >= d_GOFF[i]) g = i;
        int local = t - d_GOFF[g];
        int w = d_GW[g];
        int y = (int)((unsigned)local / (unsigned)w);
        int x = local - y*w;
        const float* __restrict__ q = ws + d_XOFF[g];

        float ctx[24];
        if (y >= 4 && x >= 4 && x < w-4) {
            const float* base = q + y*w + x;
            #pragma unroll
            for (int k = 0; k < 24; ++k)
                ctx[k] = base[d_DR[k]*w + d_DC[k]];
        } else {
            #pragma unroll
            for (int k = 0; k < 24; ++k) {
                int yy = y + d_DR[k];
                int xx = x + d_DC[k];
                float v = 0.0f;
                if (yy >= 0 && (unsigned)xx < (unsigned)w) v = q[yy*w + xx];
                ctx[k] = v;
            }
        }

        float h0[24];
        #pragma unroll
        for (int j = 0; j < 24; ++j) h0[j] = b0[j];
        #pragma unroll
        for (int k = 0; k < 24; ++k) {
            float c = ctx[k];
            #pragma unroll
            for (int j = 0; j < 24; ++j) h0[j] = fmaf(c, w0[k*24+j], h0[j]);
        }
        #pragma unroll
        for (int j = 0; j < 24; ++j) h0[j] = fmaxf(h0[j], 0.0f);

        float h1[24];
        #pragma unroll
        for (int j = 0; j < 24; ++j) h1[j] = b1[j];
        #pragma unroll
        for (int k = 0; k < 24; ++k) {
            float c = h0[k];
            #pragma unroll
            for (int j = 0; j < 24; ++j) h1[j] = fmaf(c, w1[k*24+j], h1[j]);
        }
        #pragma unroll
        for (int j = 0; j < 24; ++j) h1[j] = fmaxf(h1[j], 0.0f);

        float o0 = bo[0], o1 = bo[1];
        #pragma unroll
        for (int j = 0; j < 24; ++j) {
            o0 = fmaf(h1[j], wo[2*j+0], o0);
            o1 = fmaf(h1[j], wo[2*j+1], o1);
        }

        float mu = o0;
        float ls = fminf(fmaxf(o1, -LSC), LSC);
        float inv_s = __expf(0.5f * ls);

        float xv = q[y*w + x];
        float a = xv + 0.5f - mu;
        float b = xv - 0.5f - mu;
        float ka = __expf(-fabsf(a) * inv_s);
        float kb = __expf(-fabsf(b) * inv_s);
        float sa = copysignf(1.0f, a);
        float sb = copysignf(1.0f, b);
        float proba = 0.5f * (sb*(kb - 1.0f) - sa*(ka - 1.0f));
        proba = fmaxf(proba, 1.52587890625e-05f);
        rate = -__log2f(proba);
        out_rate[t] = rate;
    }

    __shared__ float sm[256];
    sm[threadIdx.x] = rate;
    __syncthreads();
    #pragma unroll
    for (int st = 128; st > 0; st >>= 1) {
        if (threadIdx.x < st) sm[threadIdx.x] += sm[threadIdx.x + st];
        __syncthreads();
    }
    if (threadIdx.x == 0) bsum[ablk] = sm[0];
}

// ---------------- fused level: pre(7x7 SAME) + convT8x8s2 + crop, LDS-staged ----
// block handles a 32x32 output tile of one channel; blocks [0,AB) do ARM slice.
template<int CH,int H,int W,int HT,int WT>
__global__ __launch_bounds__(256) void k_level(
    const float* __restrict__ src, float* __restrict__ dst,
    const float* __restrict__ k7, const float* __restrict__ k8,
    const float* __restrict__ ws,
    const float* __restrict__ w0, const float* __restrict__ b0,
    const float* __restrict__ w1, const float* __restrict__ b1,
    const float* __restrict__ wo, const float* __restrict__ bo,
    float* __restrict__ out_rate, float* __restrict__ bsum,
    int arm_off, int arm_cnt)
{
    if ((int)blockIdx.x < arm_cnt) {
        arm_body(ws, w0, b0, w1, b1, wo, bo, out_rate, bsum, arm_off + blockIdx.x);
        return;
    }
    constexpr int HB=(HT+1)/2, WB=(WT+1)/2;
    constexpr int TBH=(HB+15)/16, TBW=(WB+15)/16;
    int blk = blockIdx.x - arm_cnt;
    int c   = blk / (TBH*TBW);
    int r2  = blk - c*(TBH*TBW);
    int tpy = r2 / TBW, tpx = r2 - (r2/TBW)*TBW;
    int IR0 = tpy*16 - 5, IC0 = tpx*16 - 5;   // input tile origin (26x26)

    __shared__ float in_t[26*26];
    __shared__ float pre_t[20*20];

    const float* __restrict__ sc = src + c*H*W;
    for (int i = threadIdx.x; i < 676; i += 256) {
        int r = i/26, col = i - (i/26)*26;
        int gy = IR0 + r, gx = IC0 + col;
        in_t[i] = (gy >= 0 && gy < H && gx >= 0 && gx < W) ? sc[gy*W + gx] : 0.0f;
    }
    __syncthreads();

    // pre tile: 20x20 at global (IR0+3+r, IC0+3+s); zero outside image (ups pads with 0)
    for (int i = threadIdx.x; i < 400; i += 256) {
        int r = i/20, s = i - (i/20)*20;
        int gy = IR0 + 3 + r, gx = IC0 + 3 + s;
        float acc = 0.0f;
        if (gy >= 0 && gy < H && gx >= 0 && gx < W) {
            #pragma unroll
            for (int a = 0; a < 7; ++a)
                #pragma unroll
                for (int b = 0; b < 7; ++b)
                    acc = fmaf(in_t[(r+a)*26 + (s+b)], k7[a*7+b], acc);
        }
        pre_t[i] = acc;
    }
    __syncthreads();

    int ty = threadIdx.x >> 4, tx = threadIdx.x & 15;
    int pb = tpy*16 + ty, qb = tpx*16 + tx;
    if (pb >= HB || qb >= WB) return;
    float* __restrict__ dc = dst + (c+1)*HT*WT;
    #pragma unroll
    for (int pp = 0; pp < 2; ++pp) {
        int p = 2*pb + pp;
        if (p >= HT) break;
        #pragma unroll
        for (int qq = 0; qq < 2; ++qq) {
            int q = 2*qb + qq;
            if (q >= WT) continue;
            float acc = 0.0f;
            #pragma unroll
            for (int t = 0; t < 4; ++t)
                #pragma unroll
                for (int u = 0; u < 4; ++u)
                    acc = fmaf(pre_t[(ty+pp+t)*20 + (tx+qq+u)], k8[(pp+2*t)*8 + (qq+2*u)], acc);
            dc[p*WT + q] = acc;
        }
    }
}

// ---------------- 4a. fused 1x1 convs: 7 -> relu 48 -> 6 (+bpd reduce in block 0)
__global__ __launch_bounds__(256) void k_syn01(
    const float* __restrict__ x0,
    const float* __restrict__ w0, const float* __restrict__ b0,
    const float* __restrict__ w1, const float* __restrict__ b1,
    float* __restrict__ s1,
    const float* __restrict__ bsum, float* __restrict__ out_bpd)
{
    if (blockIdx.x == 0 && blockIdx.y == 0) {
        __shared__ float sm[256];
        float s = 0.0f;
        for (int i = threadIdx.x; i < NB_ARM; i += 256) s += bsum[i];
        sm[threadIdx.x] = s;
        __syncthreads();
        #pragma unroll
        for (int st = 128; st > 0; st >>= 1) {
            if (threadIdx.x < st) sm[threadIdx.x] += sm[threadIdx.x + st];
            __syncthreads();
        }
        if (threadIdx.x == 0) out_bpd[0] = sm[0] * (1.0f/2764800.0f);
    }
    int x = blockIdx.x*256 + threadIdx.x;
    int y = blockIdx.y;
    int pix = y*1280 + x;
    float in[7];
    #pragma unroll
    for (int c = 0; c < 7; ++c) in[c] = x0[c*921600 + pix];
    float h[48];
    #pragma unroll
    for (int o = 0; o < 48; ++o) {
        float a = b0[o];
        #pragma unroll
        for (int c = 0; c < 7; ++c) a = fmaf(in[c], w0[o*7 + c], a);
        h[o] = fmaxf(a, 0.0f);
    }
    #pragma unroll
    for (int o = 0; o < 6; ++o) {
        float a = b1[o];
        #pragma unroll
        for (int c = 0; c < 48; ++c) a = fmaf(h[c], w1[o*48 + c], a);
        s1[o*921600 + pix] = a;
    }
}

// ---------------- 4b. s2 = relu(conv3x3(s1)+b2 + s1) ----------------
__global__ __launch_bounds__(256) void k_s2(
    const float* __restrict__ s1,
    const float* __restrict__ w2, const float* __restrict__ b2,
    float* __restrict__ s2)
{
    int x = blockIdx.x*256 + threadIdx.x;
    int y = blockIdx.y;
    int pix = y*1280 + x;
    float acc[6];
    #pragma unroll
    for (int o = 0; o < 6; ++o) acc[o] = b2[o];
    if (x >= 1 && x < 1279 && y >= 1 && y < 719) {
        #pragma unroll
        for (int ci = 0; ci < 6; ++ci) {
            const float* p = s1 + ci*921600 + pix;
            #pragma unroll
            for (int dy = 0; dy < 3; ++dy)
                #pragma unroll
                for (int dx = 0; dx < 3; ++dx) {
                    float v = p[(dy-1)*1280 + dx - 1];
                    #pragma unroll
                    for (int o = 0; o < 6; ++o)
                        acc[o] = fmaf(v, w2[(o*6 + ci)*9 + dy*3 + dx], acc[o]);
                }
        }
    } else {
        #pragma unroll
        for (int ci = 0; ci < 6; ++ci) {
            const float* p = s1 + ci*921600;
            #pragma unroll
            for (int dy = 0; dy < 3; ++dy) {
                int yy = y + dy - 1;
                if (yy < 0 || yy >= 720) continue;
                #pragma unroll
                for (int dx = 0; dx < 3; ++dx) {
                    int xx = x + dx - 1;
                    if (xx < 0 || xx >= 1280) continue;
                    float v = p[yy*1280 + xx];
                    #pragma unroll
                    for (int o = 0; o < 6; ++o)
                        acc[o] = fmaf(v, w2[(o*6 + ci)*9 + dy*3 + dx], acc[o]);
                }
            }
        }
    }
    #pragma unroll
    for (int o = 0; o < 6; ++o)
        s2[o*921600 + pix] = fmaxf(acc[o] + s1[o*921600 + pix], 0.0f);
}

// ---------------- 4c. s3 = conv3x3(s2)+b3 + s2 ; emit mu / scale ----------------
__global__ __launch_bounds__(256) void k_s3(
    const float* __restrict__ s2,
    const float* __restrict__ w3, const float* __restrict__ b3,
    float* __restrict__ out)
{
    int x = blockIdx.x*256 + threadIdx.x;
    int y = blockIdx.y;
    int pix = y*1280 + x;
    float acc[6];
    #pragma unroll
    for (int o = 0; o < 6; ++o) acc[o] = b3[o];
    if (x >= 1 && x < 1279 && y >= 1 && y < 719) {
        #pragma unroll
        for (int ci = 0; ci < 6; ++ci) {
            const float* p = s2 + ci*921600 + pix;
            #pragma unroll
            for (int dy = 0; dy < 3; ++dy)
                #pragma unroll
                for (int dx = 0; dx < 3; ++dx) {
                    float v = p[(dy-1)*1280 + dx - 1];
                    #pragma unroll
                    for (int o = 0; o < 6; ++o)
                        acc[o] = fmaf(v, w3[(o*6 + ci)*9 + dy*3 + dx], acc[o]);
                }
        }
    } else {
        #pragma unroll
        for (int ci = 0; ci < 6; ++ci) {
            const float* p = s2 + ci*921600;
            #pragma unroll
            for (int dy = 0; dy < 3; ++dy) {
                int yy = y + dy - 1;
                if (yy < 0 || yy >= 720) continue;
                #pragma unroll
                for (int dx = 0; dx < 3; ++dx) {
                    int xx = x + dx - 1;
                    if (xx < 0 || xx >= 1280) continue;
                    float v = p[yy*1280 + xx];
                    #pragma unroll
                    for (int o = 0; o < 6; ++o)
                        acc[o] = fmaf(v, w3[(o*6 + ci)*9 + dy*3 + dx], acc[o]);
                }
            }
        }
    }
    #pragma unroll
    for (int o = 0; o < 6; ++o) {
        float v = acc[o] + s2[o*921600 + pix];
        if (o < 3) {
            out[o*921600 + pix] = v;
        } else {
            float ls = fminf(fmaxf(v, -LSC), LSC);
            out[2764800 + (o-3)*921600 + pix] = __expf(-0.5f * ls);
        }
    }
}

// ---------------- host ----------------
extern "C" void kernel_launch(void* const* d_in, const int* in_sizes, int n_in,
                              void* d_out, int out_size, void* d_ws, size_t ws_size,
                              hipStream_t stream)
{
    const float* lat[7];
    for (int i = 0; i < 7; ++i) lat[i] = (const float*)d_in[i];
    const float* arm_w0  = (const float*)d_in[7];
    const float* arm_b0  = (const float*)d_in[8];
    const float* arm_w1  = (const float*)d_in[9];
    const float* arm_b1  = (const float*)d_in[10];
    const float* arm_wo  = (const float*)d_in[11];
    const float* arm_bo  = (const float*)d_in[12];
    const float* pre_k   = (const float*)d_in[13];
    const float* ups_k   = (const float*)d_in[14];
    const float* syn_w0  = (const float*)d_in[15];
    const float* syn_b0  = (const float*)d_in[16];
    const float* syn_w1  = (const float*)d_in[17];
    const float* syn_b1  = (const float*)d_in[18];
    const float* syn_w2  = (const float*)d_in[19];
    const float* syn_b2  = (const float*)d_in[20];
    const float* syn_w3  = (const float*)d_in[21];
    const float* syn_b3  = (const float*)d_in[22];

    float* out = (float*)d_out;
    float* ws  = (float*)d_ws;
    float* rate = out + RATE_OFF;
    float* bsum = ws + BSUM_OFF;

    k_quant<<<dim3(NB_ARM), dim3(256), 0, stream>>>(
        lat[0],lat[1],lat[2],lat[3],lat[4],lat[5],lat[6], ws);

    // level kernels carry ARM slices: counts {1100,1100,1100,1100,400,0}
    #define ARM_ARGS ws, arm_w0, arm_b0, arm_w1, arm_b1, arm_wo, arm_bo, rate, bsum
    // s=0: lvl6(12x20) -> lvl5(23x40), CH=1, LB = 1*1*2 = 2
    k_level<1,12,20,23,40><<<dim3(1100+2),   dim3(256), 0, stream>>>(
        ws+8191840, ws+8190000, pre_k+0*49, ups_k+0*64, ARM_ARGS, 0, 1100);
    // s=1: lvl5(23x40) -> lvl4(45x80), CH=2, LB = 2*2*3 = 12
    k_level<2,23,40,45,80><<<dim3(1100+12),  dim3(256), 0, stream>>>(
        ws+8190000, ws+8179200, pre_k+1*49, ups_k+1*64, ARM_ARGS, 1100, 1100);
    // s=2: lvl4(45x80) -> lvl3(90x160), CH=3, LB = 3*3*5 = 45
    k_level<3,45,80,90,160><<<dim3(1100+45), dim3(256), 0, stream>>>(
        ws+8179200, ws+8121600, pre_k+2*49, ups_k+2*64, ARM_ARGS, 2200, 1100);
    // s=3: lvl3(90x160) -> lvl2(180x320), CH=4, LB = 4*6*10 = 240
    k_level<4,90,160,180,320><<<dim3(1100+240), dim3(256), 0, stream>>>(
        ws+8121600, ws+7833600, pre_k+3*49, ups_k+3*64, ARM_ARGS, 3300, 1100);
    // s=4: lvl2(180x320) -> lvl1(360x640), CH=5, LB = 5*12*20 = 1200
    k_level<5,180,320,360,640><<<dim3(400+1200), dim3(256), 0, stream>>>(
        ws+7833600, ws+6451200, pre_k+4*49, ups_k+4*64, ARM_ARGS, 4400, 400);
    // s=5: lvl1(360x640) -> lvl0(720x1280), CH=6, LB = 6*23*40 = 5520
    k_level<6,360,640,720,1280><<<dim3(5520), dim3(256), 0, stream>>>(
        ws+6451200, ws+0, pre_k+5*49, ups_k+5*64, ARM_ARGS, 4800, 0);
    #undef ARM_ARGS

    k_syn01<<<dim3(5, 720), dim3(256), 0, stream>>>(
        ws + 0, syn_w0, syn_b0, syn_w1, syn_b1, ws + S1_OFF,
        bsum, out + BPD_OFF);
    k_s2<<<dim3(5, 720), dim3(256), 0, stream>>>(
        ws + S1_OFF, syn_w2, syn_b2, ws + 0);
    k_s3<<<dim3(5, 720), dim3(256), 0, stream>>>(
        ws + 0, syn_w3, syn_b3, out);
}